// Round 4
// baseline (148.254 us; speedup 1.0000x reference)
//
#include <hip/hip_runtime.h>

// ChamferLoss: B=4, C=3, N=M=8192 fp32.
// loss = 2 * mean_b( sum_n min_m ||pos1[b,n] - pos2[b,m]||^2 ), clamped >= 0.
// Rewrite: d = q2 + r2 - 2*dot. Track smax = max_m (dot - 0.5*r2);
// d_min = max(q2 - 2*smax, 0).
// Inner loop: refs packed in pairs -> 3 v_pk_fma_f32 (FORCED via inline asm)
// + 1 v_max3_f32 per (query, ref-pair) = 2.0 inst/pair.
//
// INSTRUMENTATION ROUND: K1 launched 3x (idempotent) so dur_us - 80 ~= 2*K1,
// resolving whether the ~40us non-fill residual is K1 or harness overhead.

#define NPTS    8192
#define NB      4
#define TOTQ    (NB * NPTS)   // 32768
#define BQ      256           // threads per block (kernel 1)
#define QT      8             // queries per thread
#define QPB     (BQ * QT)     // 2048 queries per block
#define MC      256           // refs per m-chunk
#define MP      (MC / 2)      // 128 ref pairs
#define MCHUNKS (NPTS / MC)   // 32

typedef float v2f __attribute__((ext_vector_type(2)));

// Guaranteed packed fp32 FMA: d = a*b + c on both halves (one VALU inst).
static __device__ __forceinline__ v2f pk_fma(v2f a, v2f b, v2f c) {
    v2f d;
    asm("v_pk_fma_f32 %0, %1, %2, %3" : "=v"(d) : "v"(a), "v"(b), "v"(c));
    return d;
}

__global__ __launch_bounds__(BQ) void chamfer_partial(
    const float* __restrict__ pc2,       // queries [B,3,N]
    const float* __restrict__ pc1w,      // refs    [B,3,N]
    float* __restrict__ partial,         // [MCHUNKS, TOTQ] smax partials
    float* __restrict__ out)             // zeroed here for K2's atomics
{
    // per ref-pair: {x0,x1},{y0,y1},{z0,z1},{h0,h1} -> 32 B, 16B-aligned
    __shared__ v2f lds[MP * 4];
    const int tid = threadIdx.x;
    const int b  = blockIdx.z;
    const int m0 = blockIdx.y * MC;
    const int q0 = blockIdx.x * QPB;

    if (blockIdx.x == 0 && blockIdx.y == 0 && blockIdx.z == 0 && tid == 0)
        out[0] = 0.0f;   // K2 accumulates; stream order makes this safe

    const float* refb = pc1w + b * 3 * NPTS;
    {
        int i = tid;                     // 256 threads stage 256 refs
        float rx = refb[m0 + i];
        float ry = refb[NPTS + m0 + i];
        float rz = refb[2 * NPTS + m0 + i];
        float h  = -0.5f * (rx * rx + ry * ry + rz * rz);
        float* lf = (float*)lds;
        int base = (i >> 1) * 8 + (i & 1);
        lf[base + 0] = rx;
        lf[base + 2] = ry;
        lf[base + 4] = rz;
        lf[base + 6] = h;
    }
    __syncthreads();

    const float* qb = pc2 + b * 3 * NPTS;
    v2f qx2[QT], qy2[QT], qz2[QT];
    float smax[QT];
#pragma unroll
    for (int g4 = 0; g4 < 2; ++g4) {     // 2 float4 groups -> 8 queries
        int off = q0 + g4 * (BQ * 4);
        float4 fx = ((const float4*)(qb + off))[tid];
        float4 fy = ((const float4*)(qb + NPTS + off))[tid];
        float4 fz = ((const float4*)(qb + 2 * NPTS + off))[tid];
        int j = g4 * 4;
        qx2[j+0] = (v2f){fx.x, fx.x}; qx2[j+1] = (v2f){fx.y, fx.y};
        qx2[j+2] = (v2f){fx.z, fx.z}; qx2[j+3] = (v2f){fx.w, fx.w};
        qy2[j+0] = (v2f){fy.x, fy.x}; qy2[j+1] = (v2f){fy.y, fy.y};
        qy2[j+2] = (v2f){fy.z, fy.z}; qy2[j+3] = (v2f){fy.w, fy.w};
        qz2[j+0] = (v2f){fz.x, fz.x}; qz2[j+1] = (v2f){fz.y, fz.y};
        qz2[j+2] = (v2f){fz.z, fz.z}; qz2[j+3] = (v2f){fz.w, fz.w};
    }
#pragma unroll
    for (int j = 0; j < QT; ++j) smax[j] = -1e30f;

#pragma unroll 2
    for (int p = 0; p < MP; ++p) {
        v2f rx = lds[p * 4 + 0];
        v2f ry = lds[p * 4 + 1];
        v2f rz = lds[p * 4 + 2];
        v2f rh = lds[p * 4 + 3];
#pragma unroll
        for (int j = 0; j < QT; ++j) {
            v2f s = pk_fma(qx2[j], rx, rh);
            s = pk_fma(qy2[j], ry, s);
            s = pk_fma(qz2[j], rz, s);
            smax[j] = fmaxf(smax[j], fmaxf(s[0], s[1]));  // v_max3_f32
        }
    }

    float* pbase = partial + blockIdx.y * TOTQ + b * NPTS;
#pragma unroll
    for (int g4 = 0; g4 < 2; ++g4) {
        int off = q0 + g4 * (BQ * 4);
        int j = g4 * 4;
        float4 o = make_float4(smax[j], smax[j+1], smax[j+2], smax[j+3]);
        ((float4*)(pbase + off))[tid] = o;
    }
}

__global__ __launch_bounds__(512) void chamfer_reduce(
    const float* __restrict__ pc2,
    const float* __restrict__ partial,
    float* __restrict__ out)
{
    const int g = blockIdx.x * 512 + threadIdx.x;  // query id, 64 blocks
    float smax = -1e30f;
#pragma unroll
    for (int c = 0; c < MCHUNKS; ++c)
        smax = fmaxf(smax, partial[c * TOTQ + g]);

    const int b = g >> 13;          // / NPTS
    const int n = g & (NPTS - 1);
    const float* qb = pc2 + b * 3 * NPTS;
    float qx = qb[n], qy = qb[NPTS + n], qz = qb[2 * NPTS + n];
    float q2 = qx * qx + qy * qy + qz * qz;
    float d = fmaxf(q2 - 2.0f * smax, 0.0f);

    // wave-64 reduction
#pragma unroll
    for (int off = 32; off > 0; off >>= 1)
        d += __shfl_down(d, off, 64);

    __shared__ float wsum[8];
    const int lane = threadIdx.x & 63;
    const int wid  = threadIdx.x >> 6;
    if (lane == 0) wsum[wid] = d;
    __syncthreads();
    if (threadIdx.x == 0) {
        float s = 0.0f;
#pragma unroll
        for (int w = 0; w < 8; ++w) s += wsum[w];
        atomicAdd(out, s * (2.0f / NB));   // 2 * mean over batches
    }
}

extern "C" void kernel_launch(void* const* d_in, const int* in_sizes, int n_in,
                              void* d_out, int out_size, void* d_ws, size_t ws_size,
                              hipStream_t stream) {
    const float* pc2  = (const float*)d_in[0];
    const float* pc1w = (const float*)d_in[1];
    float* out = (float*)d_out;
    float* partial = (float*)d_ws;   // MCHUNKS * TOTQ * 4 B = 4 MiB

    dim3 g1(NPTS / QPB, MCHUNKS, NB);   // (4, 32, 4) = 512 blocks
    // Launched 3x ON PURPOSE (idempotent): dur delta vs single launch
    // measures K1's true duration (top-5 rocprof rows are all harness fills).
    chamfer_partial<<<g1, BQ, 0, stream>>>(pc2, pc1w, partial, out);
    chamfer_partial<<<g1, BQ, 0, stream>>>(pc2, pc1w, partial, out);
    chamfer_partial<<<g1, BQ, 0, stream>>>(pc2, pc1w, partial, out);
    chamfer_reduce<<<TOTQ / 512, 512, 0, stream>>>(pc2, partial, out);
}

// Round 5
// 88.595 us; speedup vs baseline: 1.6734x; 1.6734x over previous
//
#include <hip/hip_runtime.h>

// ChamferLoss: B=4, C=3, N=M=8192 fp32.
// loss = 2 * mean_b( sum_n min_m ||pos1[b,n] - pos2[b,m]||^2 ), clamped >= 0.
// Rewrite: d = q2 + r2 - 2*dot. Track smax = max_m (dot - 0.5*r2);
// d_min = max(q2 - 2*smax, 0).
// Inner loop: scalar v_fma (pk_fma is NOT double-rate on CDNA4 — fp32 peak
// 157.3 TF == scalar rate). Ref-pair + v_max3_f32: 7 inst / 2 pairs.
// Occupancy: 1024 blocks (4/CU, 16 waves/CU) to hide FMA-chain + LDS latency
// (round-4 instrumentation: 512-block version ran K1 at 34us vs 12us floor).

#define NPTS    8192
#define NB      4
#define TOTQ    (NB * NPTS)   // 32768
#define BQ      256           // threads per block (kernel 1)
#define QT      8             // queries per thread
#define QPB     (BQ * QT)     // 2048 queries per block
#define MC      128           // refs per m-chunk
#define MP      (MC / 2)      // 64 ref pairs
#define MCHUNKS (NPTS / MC)   // 64

__global__ __launch_bounds__(BQ) void chamfer_partial(
    const float* __restrict__ pc2,       // queries [B,3,N]
    const float* __restrict__ pc1w,      // refs    [B,3,N]
    float* __restrict__ partial,         // [MCHUNKS, TOTQ] smax partials
    float* __restrict__ out)             // zeroed here for K2's atomics
{
    __shared__ float4 lds[MC];           // (rx, ry, rz, -0.5*r2) per ref
    const int tid = threadIdx.x;
    const int b  = blockIdx.z;
    const int m0 = blockIdx.y * MC;
    const int q0 = blockIdx.x * QPB;

    if (blockIdx.x == 0 && blockIdx.y == 0 && blockIdx.z == 0 && tid == 0)
        out[0] = 0.0f;   // K2 accumulates; stream order makes this safe

    const float* refb = pc1w + b * 3 * NPTS;
    if (tid < MC) {
        int i = tid;
        float rx = refb[m0 + i];
        float ry = refb[NPTS + m0 + i];
        float rz = refb[2 * NPTS + m0 + i];
        float h  = -0.5f * (rx * rx + ry * ry + rz * rz);
        lds[i] = make_float4(rx, ry, rz, h);
    }
    __syncthreads();

    const float* qb = pc2 + b * 3 * NPTS;
    float qx[QT], qy[QT], qz[QT], smax[QT];
#pragma unroll
    for (int g4 = 0; g4 < 2; ++g4) {     // 2 float4 groups -> 8 queries
        int off = q0 + g4 * (BQ * 4);
        float4 fx = ((const float4*)(qb + off))[tid];
        float4 fy = ((const float4*)(qb + NPTS + off))[tid];
        float4 fz = ((const float4*)(qb + 2 * NPTS + off))[tid];
        int j = g4 * 4;
        qx[j+0] = fx.x; qx[j+1] = fx.y; qx[j+2] = fx.z; qx[j+3] = fx.w;
        qy[j+0] = fy.x; qy[j+1] = fy.y; qy[j+2] = fy.z; qy[j+3] = fy.w;
        qz[j+0] = fz.x; qz[j+1] = fz.y; qz[j+2] = fz.z; qz[j+3] = fz.w;
    }
#pragma unroll
    for (int j = 0; j < QT; ++j) smax[j] = -1e30f;

#pragma unroll 4
    for (int p = 0; p < MP; ++p) {
        float4 r0 = lds[2 * p + 0];
        float4 r1 = lds[2 * p + 1];
#pragma unroll
        for (int j = 0; j < QT; ++j) {
            float s0 = fmaf(qx[j], r0.x, r0.w);
            s0 = fmaf(qy[j], r0.y, s0);
            s0 = fmaf(qz[j], r0.z, s0);
            float s1 = fmaf(qx[j], r1.x, r1.w);
            s1 = fmaf(qy[j], r1.y, s1);
            s1 = fmaf(qz[j], r1.z, s1);
            smax[j] = fmaxf(smax[j], fmaxf(s0, s1));  // v_max3_f32
        }
    }

    float* pbase = partial + blockIdx.y * TOTQ + b * NPTS;
#pragma unroll
    for (int g4 = 0; g4 < 2; ++g4) {
        int off = q0 + g4 * (BQ * 4);
        int j = g4 * 4;
        float4 o = make_float4(smax[j], smax[j+1], smax[j+2], smax[j+3]);
        ((float4*)(pbase + off))[tid] = o;
    }
}

__global__ __launch_bounds__(512) void chamfer_reduce(
    const float* __restrict__ pc2,
    const float* __restrict__ partial,
    float* __restrict__ out)
{
    const int g = blockIdx.x * 512 + threadIdx.x;  // query id, 64 blocks
    float smax = -1e30f;
#pragma unroll 8
    for (int c = 0; c < MCHUNKS; ++c)
        smax = fmaxf(smax, partial[c * TOTQ + g]);

    const int b = g >> 13;          // / NPTS
    const int n = g & (NPTS - 1);
    const float* qb = pc2 + b * 3 * NPTS;
    float qx = qb[n], qy = qb[NPTS + n], qz = qb[2 * NPTS + n];
    float q2 = qx * qx + qy * qy + qz * qz;
    float d = fmaxf(q2 - 2.0f * smax, 0.0f);

    // wave-64 reduction
#pragma unroll
    for (int off = 32; off > 0; off >>= 1)
        d += __shfl_down(d, off, 64);

    __shared__ float wsum[8];
    const int lane = threadIdx.x & 63;
    const int wid  = threadIdx.x >> 6;
    if (lane == 0) wsum[wid] = d;
    __syncthreads();
    if (threadIdx.x == 0) {
        float s = 0.0f;
#pragma unroll
        for (int w = 0; w < 8; ++w) s += wsum[w];
        atomicAdd(out, s * (2.0f / NB));   // 2 * mean over batches
    }
}

extern "C" void kernel_launch(void* const* d_in, const int* in_sizes, int n_in,
                              void* d_out, int out_size, void* d_ws, size_t ws_size,
                              hipStream_t stream) {
    const float* pc2  = (const float*)d_in[0];
    const float* pc1w = (const float*)d_in[1];
    float* out = (float*)d_out;
    float* partial = (float*)d_ws;   // MCHUNKS * TOTQ * 4 B = 8 MiB

    dim3 g1(NPTS / QPB, MCHUNKS, NB);   // (4, 64, 4) = 1024 blocks
    chamfer_partial<<<g1, BQ, 0, stream>>>(pc2, pc1w, partial, out);
    chamfer_reduce<<<TOTQ / 512, 512, 0, stream>>>(pc2, partial, out);
}

// Round 7
// 78.989 us; speedup vs baseline: 1.8769x; 1.1216x over previous
//
#include <hip/hip_runtime.h>

// ChamferLoss: B=4, C=3, N=M=8192 fp32.
// loss = 2 * mean_b( sum_n min_m ||q_n - r_m||^2 ), clamp >= 0.
// MFMA formulation: s(n,m) = q.r - 0.5*r^2 via one v_mfma_f32_32x32x16_bf16
// per 32x32 tile, fp32 split as bf16 hi+lo across the K dimension:
//   k0..k8: {x,y,z} x {hi*hi, lo*hi, hi*lo}, k9..k10: h_hi,h_lo (A) x 1.0 (B)
// (dropped lo*lo terms ~2^-16 rel; threshold 7.76 >> expected ~0.1 error).
// Rows(m)=refs -> max over rows is lane-local reg folds (v_max3), permutation-
// invariant to the A row layout. d_min = max(q2 - 2*smax, 0).
//
// ROUND-6 BUG FIX: RR was 16 with RCPR=32 -> 512 chunks/batch indexed but only
// 256 exist; ranges 8..15 read the NEXT batch's refs (smax inflated, loss
// under-estimated by ~205). RR=8 now: 8 ranges x 32 chunks x 32 pts = 8192. ✓

#define NPTS  8192
#define NB    4
#define NCH   256      // 32-point chunks per batch (8192/32)
#define RR    8        // ref ranges (1024 refs each; RR*RCPR*32 == NPTS)
#define RCPR  32       // ref chunks per range
#define QPB   4        // q-chunks per block (one per wave)

typedef float f32x16 __attribute__((ext_vector_type(16)));
typedef short bf16x8 __attribute__((ext_vector_type(8)));

static __device__ __forceinline__ unsigned int f2bf(float f) {
    unsigned int u = __float_as_uint(f);
    u += 0x7FFF + ((u >> 16) & 1);          // RNE
    return u >> 16;
}
static __device__ __forceinline__ float bf2f(unsigned int s) {
    return __uint_as_float(s << 16);
}

// ---- Phase 0: build MFMA fragment records (16 B per point per k-group) ----
// frag layout per chunk: [g0: 32 lanes x 16B][g1: 32 lanes x 16B] = 1 KB.
__global__ __launch_bounds__(256) void chamfer_prep(
    const float* __restrict__ pc2,       // queries [B,3,N]  (B operand)
    const float* __restrict__ pc1w,      // refs    [B,3,N]  (A operand)
    uint4* __restrict__ qfrag, uint4* __restrict__ rfrag,
    float* __restrict__ out)
{
    int t = blockIdx.x * 256 + threadIdx.x;   // 65536 threads
    if (t == 0) out[0] = 0.0f;                // K2 accumulates; stream-ordered
    int side = t >> 15;                       // 0 = query, 1 = ref
    int rem  = t & 32767;
    int b = rem >> 13;
    int n = rem & 8191;
    const float* src = (side ? pc1w : pc2) + b * 3 * NPTS;
    float x = src[n], y = src[NPTS + n], z = src[2 * NPTS + n];
    unsigned int xh = f2bf(x), yh = f2bf(y), zh = f2bf(z);
    unsigned int xl = f2bf(x - bf2f(xh));
    unsigned int yl = f2bf(y - bf2f(yh));
    unsigned int zl = f2bf(z - bf2f(zh));
    int chunk = n >> 5, lane = n & 31;
    uint4 g0, g1;
    if (side == 0) {  // B-side (query): k0..7=[xh,xh,xl,yh,yh,yl,zh,zh], k8..10=[zl,1,1]
        g0.x = xh | (xh << 16);
        g0.y = xl | (yh << 16);
        g0.z = yh | (yl << 16);
        g0.w = zh | (zh << 16);
        g1.x = zl | (0x3F80u << 16);
        g1.y = 0x3F80u;
        g1.z = 0u; g1.w = 0u;
    } else {          // A-side (ref): k0..7=[xh,xl,xh,yh,yl,yh,zh,zl], k8..10=[zh,hh,hl]
        float h = -0.5f * (x * x + y * y + z * z);
        unsigned int hh = f2bf(h);
        unsigned int hl = f2bf(h - bf2f(hh));
        g0.x = xh | (xl << 16);
        g0.y = xh | (yh << 16);
        g0.z = yl | (yh << 16);
        g0.w = zh | (zl << 16);
        g1.x = zh | (hh << 16);
        g1.y = hl;
        g1.z = 0u; g1.w = 0u;
    }
    uint4* dst = (side ? rfrag : qfrag) + ((b * NCH + chunk) * 64 + lane);
    dst[0]  = g0;   // g=0
    dst[32] = g1;   // g=1 (+512 B)
}

// ---- Phase 1: MFMA tiles + per-query running max ----
__global__ __launch_bounds__(256) void chamfer_mfma(
    const uint4* __restrict__ qfrag, const uint4* __restrict__ rfrag,
    float* __restrict__ partial)         // [B, RR, NPTS]
{
    __shared__ uint4 slds[2048];         // 32 ref chunks = 32 KB
    const int tid  = threadIdx.x;
    const int b    = blockIdx.z;
    const int rr   = blockIdx.y;
    const int wave = tid >> 6;
    const int lane = tid & 63;

    // stage this range's ref fragments (contiguous 32 KB) into LDS
    const uint4* rsrc = rfrag + (b * NCH + rr * RCPR) * 64;
#pragma unroll
    for (int i = 0; i < 8; ++i)
        slds[tid + i * 256] = rsrc[tid + i * 256];
    __syncthreads();

    // wave-resident query fragment (B operand), loaded once
    const int qc = blockIdx.x * QPB + wave;
    uint4 bq_u = qfrag[(b * NCH + qc) * 64 + (lane >> 5) * 32 + (lane & 31)];
    bf16x8 bq = __builtin_bit_cast(bf16x8, bq_u);

    f32x16 zero;
#pragma unroll
    for (int i = 0; i < 16; ++i) zero[i] = 0.0f;

    float rm0 = -3e38f, rm1 = -3e38f, rm2 = -3e38f, rm3 = -3e38f;
    const int abase = (lane >> 5) * 32 + (lane & 31);
#pragma unroll 2
    for (int c = 0; c < RCPR; ++c) {
        bf16x8 a = __builtin_bit_cast(bf16x8, slds[c * 64 + abase]);
        f32x16 d = __builtin_amdgcn_mfma_f32_32x32x16_bf16(a, bq, zero, 0, 0, 0);
        // rows = refs: fold 16 row-values into 4 independent running maxes
        rm0 = fmaxf(rm0, fmaxf(d[0],  d[1]));   // v_max3 chains
        rm0 = fmaxf(rm0, fmaxf(d[2],  d[3]));
        rm1 = fmaxf(rm1, fmaxf(d[4],  d[5]));
        rm1 = fmaxf(rm1, fmaxf(d[6],  d[7]));
        rm2 = fmaxf(rm2, fmaxf(d[8],  d[9]));
        rm2 = fmaxf(rm2, fmaxf(d[10], d[11]));
        rm3 = fmaxf(rm3, fmaxf(d[12], d[13]));
        rm3 = fmaxf(rm3, fmaxf(d[14], d[15]));
    }
    float rm = fmaxf(fmaxf(rm0, rm1), fmaxf(rm2, rm3));
    // lanes l and l^32 hold the two row-halves of the same query column
    rm = fmaxf(rm, __shfl_xor(rm, 32, 64));
    if (lane < 32)
        partial[(b * RR + rr) * NPTS + qc * 32 + lane] = rm;
}

// ---- Phase 2: finalize ----
__global__ __launch_bounds__(512) void chamfer_reduce(
    const float* __restrict__ pc2,
    const float* __restrict__ partial,
    float* __restrict__ out)
{
    const int g = blockIdx.x * 512 + threadIdx.x;   // query id
    const int b = g >> 13, n = g & 8191;
    float smax = -3e38f;
#pragma unroll
    for (int c = 0; c < RR; ++c)
        smax = fmaxf(smax, partial[(b * RR + c) * NPTS + n]);

    const float* qb = pc2 + b * 3 * NPTS;
    float qx = qb[n], qy = qb[NPTS + n], qz = qb[2 * NPTS + n];
    float q2 = qx * qx + qy * qy + qz * qz;
    float d = fmaxf(q2 - 2.0f * smax, 0.0f);

#pragma unroll
    for (int off = 32; off > 0; off >>= 1)
        d += __shfl_down(d, off, 64);

    __shared__ float wsum[8];
    const int lane = threadIdx.x & 63;
    const int wid  = threadIdx.x >> 6;
    if (lane == 0) wsum[wid] = d;
    __syncthreads();
    if (threadIdx.x == 0) {
        float s = 0.0f;
#pragma unroll
        for (int w = 0; w < 8; ++w) s += wsum[w];
        atomicAdd(out, s * (2.0f / NB));   // 2 * mean over batches
    }
}

extern "C" void kernel_launch(void* const* d_in, const int* in_sizes, int n_in,
                              void* d_out, int out_size, void* d_ws, size_t ws_size,
                              hipStream_t stream) {
    const float* pc2  = (const float*)d_in[0];
    const float* pc1w = (const float*)d_in[1];
    float* out = (float*)d_out;
    uint4* qfrag   = (uint4*)d_ws;                          // 1 MiB
    uint4* rfrag   = (uint4*)((char*)d_ws + (1u << 20));    // 1 MiB
    float* partial = (float*)((char*)d_ws + (2u << 20));    // 1 MiB

    chamfer_prep<<<256, 256, 0, stream>>>(pc2, pc1w, qfrag, rfrag, out);
    dim3 g1(NCH / QPB, RR, NB);   // (64, 8, 4) = 2048 blocks
    chamfer_mfma<<<g1, 256, 0, stream>>>(qfrag, rfrag, partial);
    chamfer_reduce<<<NB * NPTS / 512, 512, 0, stream>>>(pc2, partial, out);
}

// Round 8
// 74.816 us; speedup vs baseline: 1.9816x; 1.0558x over previous
//
#include <hip/hip_runtime.h>

// ChamferLoss: B=4, C=3, N=M=8192 fp32.
// loss = 2 * mean_b( sum_n min_m ||q_n - r_m||^2 ), clamp >= 0.
// s(n,m) = q.r - 0.5*r^2 via v_mfma_f32_32x32x16_bf16, fp32 split as bf16
// hi+lo across K: k0..k8 {x,y,z}x{hh,lh,hl}, k9..k10 h_hi,h_lo (A) x 1.0 (B).
// Verified exact (absmax 0.0) in round 7. d_min = max(q2 - 2*smax, 0).
//
// ROUND 8: prep merged into the MFMA kernel (refs converted fp32->bf16 pair
// straight into LDS; query B-fragment built per-lane in regs). Eliminates the
// prep dispatch and the qfrag/rfrag round-trip through the poisoned d_ws.

#define NPTS  8192
#define NB    4
#define NCH   256      // 32-point q-chunks per batch
#define RR    8        // ref ranges (1024 refs each)
#define RCPR  32       // ref chunks per range
#define WPB   8        // waves per block = q-chunks per block
#define BT    (WPB*64) // 512 threads

typedef float f32x16 __attribute__((ext_vector_type(16)));
typedef short bf16x8 __attribute__((ext_vector_type(8)));

static __device__ __forceinline__ unsigned int f2bf(float f) {
    unsigned int u = __float_as_uint(f);
    u += 0x7FFF + ((u >> 16) & 1);          // RNE
    return u >> 16;
}
static __device__ __forceinline__ float bf2f(unsigned int s) {
    return __uint_as_float(s << 16);
}

// ---- Phase 1: convert + MFMA tiles + per-query running max ----
__global__ __launch_bounds__(BT) void chamfer_mfma(
    const float* __restrict__ pc2,       // queries [B,3,N]  (B operand)
    const float* __restrict__ pc1w,      // refs    [B,3,N]  (A operand)
    float* __restrict__ partial,         // [B, RR, NPTS] smax partials
    float* __restrict__ out)             // zeroed here for K2's atomics
{
    __shared__ uint4 slds[RCPR * 64];    // 32 KB: A-fragments for 1024 refs
    const int tid  = threadIdx.x;
    const int b    = blockIdx.z;
    const int rr   = blockIdx.y;
    const int wave = tid >> 6;
    const int lane = tid & 63;

    if (blockIdx.x == 0 && rr == 0 && b == 0 && tid == 0)
        out[0] = 0.0f;   // K2 accumulates; stream order makes this safe

    // stage + convert this range's 1024 refs into A-fragment layout
    const float* refb = pc1w + b * 3 * NPTS + rr * (RCPR * 32);
#pragma unroll
    for (int j = 0; j < 2; ++j) {
        int i = tid + j * BT;            // 0..1023, coalesced
        float x = refb[i], y = refb[NPTS + i], z = refb[2 * NPTS + i];
        unsigned xh = f2bf(x), yh = f2bf(y), zh = f2bf(z);
        unsigned xl = f2bf(x - bf2f(xh));
        unsigned yl = f2bf(y - bf2f(yh));
        unsigned zl = f2bf(z - bf2f(zh));
        float h = -0.5f * (x * x + y * y + z * z);
        unsigned hh = f2bf(h);
        unsigned hl = f2bf(h - bf2f(hh));
        int c = i >> 5, l32 = i & 31;
        // k0..7 = [xh,xl,xh,yh,yl,yh,zh,zl], k8..15 = [zh,hh,hl,0,...]
        slds[c * 64 + l32] =
            make_uint4(xh | (xl << 16), xh | (yh << 16),
                       yl | (yh << 16), zh | (zl << 16));
        slds[c * 64 + 32 + l32] = make_uint4(zh | (hh << 16), hl, 0u, 0u);
    }

    // per-lane query B-fragment (column = lane&31)
    const int qc = blockIdx.x * WPB + wave;
    const int qn = qc * 32 + (lane & 31);
    const float* qb = pc2 + b * 3 * NPTS;
    {
    }
    float x = qb[qn], y = qb[NPTS + qn], z = qb[2 * NPTS + qn];
    unsigned xh = f2bf(x), yh = f2bf(y), zh = f2bf(z);
    unsigned xl = f2bf(x - bf2f(xh));
    unsigned yl = f2bf(y - bf2f(yh));
    unsigned zl = f2bf(z - bf2f(zh));
    // k0..7 = [xh,xh,xl,yh,yh,yl,zh,zh], k8..15 = [zl,1,1,0,...]
    uint4 bu = (lane < 32)
        ? make_uint4(xh | (xh << 16), xl | (yh << 16),
                     yh | (yl << 16), zh | (zh << 16))
        : make_uint4(zl | (0x3F80u << 16), 0x3F80u, 0u, 0u);
    bf16x8 bq = __builtin_bit_cast(bf16x8, bu);

    __syncthreads();

    f32x16 zero;
#pragma unroll
    for (int i = 0; i < 16; ++i) zero[i] = 0.0f;

    float rm0 = -3e38f, rm1 = -3e38f, rm2 = -3e38f, rm3 = -3e38f;
    const int abase = (lane >> 5) * 32 + (lane & 31);
#pragma unroll 2
    for (int c = 0; c < RCPR; ++c) {
        bf16x8 a = __builtin_bit_cast(bf16x8, slds[c * 64 + abase]);
        f32x16 d = __builtin_amdgcn_mfma_f32_32x32x16_bf16(a, bq, zero, 0, 0, 0);
        rm0 = fmaxf(rm0, fmaxf(d[0],  d[1]));   // rows = refs
        rm0 = fmaxf(rm0, fmaxf(d[2],  d[3]));
        rm1 = fmaxf(rm1, fmaxf(d[4],  d[5]));
        rm1 = fmaxf(rm1, fmaxf(d[6],  d[7]));
        rm2 = fmaxf(rm2, fmaxf(d[8],  d[9]));
        rm2 = fmaxf(rm2, fmaxf(d[10], d[11]));
        rm3 = fmaxf(rm3, fmaxf(d[12], d[13]));
        rm3 = fmaxf(rm3, fmaxf(d[14], d[15]));
    }
    float rm = fmaxf(fmaxf(rm0, rm1), fmaxf(rm2, rm3));
    // lanes l and l^32 hold the two row-halves of the same query column
    rm = fmaxf(rm, __shfl_xor(rm, 32, 64));
    if (lane < 32)
        partial[(b * RR + rr) * NPTS + qc * 32 + lane] = rm;
}

// ---- Phase 2: finalize ----
__global__ __launch_bounds__(512) void chamfer_reduce(
    const float* __restrict__ pc2,
    const float* __restrict__ partial,
    float* __restrict__ out)
{
    const int g = blockIdx.x * 512 + threadIdx.x;   // query id
    const int b = g >> 13, n = g & 8191;
    float smax = -3e38f;
#pragma unroll
    for (int c = 0; c < RR; ++c)
        smax = fmaxf(smax, partial[(b * RR + c) * NPTS + n]);

    const float* qb = pc2 + b * 3 * NPTS;
    float qx = qb[n], qy = qb[NPTS + n], qz = qb[2 * NPTS + n];
    float q2 = qx * qx + qy * qy + qz * qz;
    float d = fmaxf(q2 - 2.0f * smax, 0.0f);

#pragma unroll
    for (int off = 32; off > 0; off >>= 1)
        d += __shfl_down(d, off, 64);

    __shared__ float wsum[8];
    const int lane = threadIdx.x & 63;
    const int wid  = threadIdx.x >> 6;
    if (lane == 0) wsum[wid] = d;
    __syncthreads();
    if (threadIdx.x == 0) {
        float s = 0.0f;
#pragma unroll
        for (int w = 0; w < 8; ++w) s += wsum[w];
        atomicAdd(out, s * (2.0f / NB));   // 2 * mean over batches
    }
}

extern "C" void kernel_launch(void* const* d_in, const int* in_sizes, int n_in,
                              void* d_out, int out_size, void* d_ws, size_t ws_size,
                              hipStream_t stream) {
    const float* pc2  = (const float*)d_in[0];
    const float* pc1w = (const float*)d_in[1];
    float* out = (float*)d_out;
    float* partial = (float*)d_ws;   // B * RR * NPTS * 4 = 1 MiB

    dim3 g1(NCH / WPB, RR, NB);      // (32, 8, 4) = 1024 blocks
    chamfer_mfma<<<g1, BT, 0, stream>>>(pc2, pc1w, partial, out);
    chamfer_reduce<<<NB * NPTS / 512, 512, 0, stream>>>(pc2, partial, out);
}